// Round 13
// baseline (720.077 us; speedup 1.0000x reference)
//
#include <hip/hip_runtime.h>
#include <cstddef>

// ---------------------------------------------------------------------------
// MegNet block, round 13: R12 structure (64-edge tile, 4-chain ILP) with
// EF aliased back into the H region (LDS 48KB -> 40KB -> 4 blocks/CU,
// launch_bounds(256,4)) and vb-gathers issued before ef-stream loads.
// E=800000, N=100000, D=64, H=128.
// ---------------------------------------------------------------------------

typedef __attribute__((ext_vector_type(8))) short short8;   // 8 bf16
typedef __attribute__((ext_vector_type(4))) float f32x4;
typedef __attribute__((ext_vector_type(4))) unsigned int u32x4;
typedef __attribute__((ext_vector_type(2))) unsigned int u32x2;

__device__ __forceinline__ float sp(float x) {
    return fmaxf(x, 0.f) + __logf(1.f + __expf(-fabsf(x)));
}
__device__ __forceinline__ unsigned short f2bf(float x) {
    unsigned int u = __float_as_uint(x);
    u += 0x7fff + ((u >> 16) & 1);          // RNE
    return (unsigned short)(u >> 16);
}
__device__ __forceinline__ unsigned int cvtpk(float lo, float hi) {
    unsigned int r;
    asm("v_cvt_pk_bf16_f32 %0, %1, %2" : "=v"(r) : "v"(lo), "v"(hi));
    return r;
}
__device__ __forceinline__ u32x4 pack8(f32x4 a, f32x4 b) {
    u32x4 r;
    r.x = cvtpk(a[0], a[1]); r.y = cvtpk(a[2], a[3]);
    r.z = cvtpk(b[0], b[1]); r.w = cvtpk(b[2], b[3]);
    return r;
}
__device__ __forceinline__ float bflo(unsigned int u) { return __uint_as_float(u << 16); }
__device__ __forceinline__ float bfhi(unsigned int u) { return __uint_as_float(u & 0xffff0000u); }
// 16B-chunk XOR swizzle
__device__ __forceinline__ int swz(int row, int chunk, int stride) {
    return row * stride + 128 * (chunk >> 3) + 16 * ((chunk & 7) ^ (row & 7));
}
__device__ __forceinline__ f32x4 mfma16(short8 a, short8 b, f32x4 c) {
    return __builtin_amdgcn_mfma_f32_16x16x32_bf16(a, b, c, 0, 0, 0);
}

// ---------------- weight transpose+bf16 prep (+ fused dst histogram) -------
__global__ __launch_bounds__(256) void wprep(
    const float* __restrict__ Wpe, const float* __restrict__ We0,
    const float* __restrict__ We1, const float* __restrict__ We2,
    const float* __restrict__ Wn0, const float* __restrict__ Wn1,
    const float* __restrict__ Wn2, const float* __restrict__ Wpn,
    unsigned short* __restrict__ out,
    const int* __restrict__ dst, int* __restrict__ cnt, int E)
{
    int idx = blockIdx.x * 256 + threadIdx.x;
    for (int i = idx; i < E; i += 384 * 256) atomicAdd(&cnt[dst[i]], 1);

    const float* src; int K, N, base;
    if      (idx < 4096)  { src = Wpe; K = 64;  N = 64;  base = 0; }
    else if (idx < 28672) { src = We0; K = 192; N = 128; base = 4096; }
    else if (idx < 45056) { src = We1; K = 128; N = 128; base = 28672; }
    else if (idx < 53248) { src = We2; K = 128; N = 64;  base = 45056; }
    else if (idx < 69632) { src = Wn0; K = 128; N = 128; base = 53248; }
    else if (idx < 86016) { src = Wn1; K = 128; N = 128; base = 69632; }
    else if (idx < 94208) { src = Wn2; K = 128; N = 64;  base = 86016; }
    else if (idx < 98304) { src = Wpn; K = 64;  N = 64;  base = 94208; }
    else return;
    int r = idx - base, n = r / K, k = r % K;
    out[idx] = f2bf(src[(size_t)k * N + n]);
}

// ---------------- pre-dense node MLP (MFMA) -> bf16 v ----------------------
__global__ __launch_bounds__(256) void pre_node_kernel(
    const float* __restrict__ nf, const unsigned short* __restrict__ WpnT,
    const float* __restrict__ b, unsigned short* __restrict__ vb, int N)
{
    __shared__ __align__(16) char lds[16384];
    const int t = threadIdx.x, w = t >> 6, l = t & 63;
    const int l15 = l & 15, l4 = l >> 4;
    const int n0 = blockIdx.x * 64;

#pragma unroll
    for (int rr = 0; rr < 2; ++rr) {
        int f = t + 256 * rr;
        int e = f >> 3, c = f & 7;
        int n = n0 + e; if (n >= N) n = N - 1;
        const float* p = nf + (size_t)n * 64 + c * 8;
        f32x4 x0 = *(const f32x4*)p, x1 = *(const f32x4*)(p + 4);
        *(u32x4*)(lds + swz(e, c, 128)) = pack8(x0, x1);
    }
    __syncthreads();
    {
        const int nr = w * 16;
        short8 A0 = *(const short8*)(WpnT + (nr + l15) * 64 + l4 * 8);
        short8 A1 = *(const short8*)(WpnT + (nr + l15) * 64 + 32 + l4 * 8);
        f32x4 bb = *(const f32x4*)(b + nr + l4 * 4);
        const int ochunk = (nr >> 3) + (l4 >> 1), obyte = (l4 & 1) * 8;
#pragma unroll
        for (int tt = 0; tt < 4; ++tt) {
            short8 b0 = *(const short8*)(lds + swz(tt * 16 + l15, l4, 128));
            short8 b1 = *(const short8*)(lds + swz(tt * 16 + l15, 4 + l4, 128));
            f32x4 acc = {0.f, 0.f, 0.f, 0.f};
            acc = mfma16(A0, b0, acc);
            acc = mfma16(A1, b1, acc);
            u32x2 p;
            p.x = cvtpk(sp(acc[0] + bb[0]), sp(acc[1] + bb[1]));
            p.y = cvtpk(sp(acc[2] + bb[2]), sp(acc[3] + bb[3]));
            *(u32x2*)(lds + 8192 + swz(tt * 16 + l15, ochunk, 128) + obyte) = p;
        }
    }
    __syncthreads();
#pragma unroll
    for (int rr = 0; rr < 2; ++rr) {
        int f = t + 256 * rr;
        int e = f >> 3, c = f & 7;
        int n = n0 + e;
        if (n < N) {
            u32x4 d = *(const u32x4*)(lds + 8192 + swz(e, c, 128));
            *(u32x4*)(vb + (size_t)n * 64 + c * 8) = d;
        }
    }
}

// -------- pre-dense attr + fold u into edge/node layer-0 biases ------------
__global__ void pre_attr_kernel(
    const float* __restrict__ ga, const float* __restrict__ Wpa, const float* __restrict__ bpa,
    const float* __restrict__ eW0, const float* __restrict__ eb0,
    const float* __restrict__ nW0, const float* __restrict__ nb0,
    float* __restrict__ u, float* __restrict__ c0e, float* __restrict__ c0n)
{
    __shared__ float us[64];
    const int t = threadIdx.x;
    if (t < 64) {
        float acc = bpa[t];
        for (int k = 0; k < 64; ++k) acc += ga[k] * Wpa[k * 64 + t];
        float uu = sp(acc);
        us[t] = uu;
        u[t] = uu;
    }
    __syncthreads();
    if (t < 128) {
        float acc = eb0[t];
        for (int k = 0; k < 64; ++k) acc += us[k] * eW0[(192 + k) * 128 + t];
        c0e[t] = acc;
        float accn = nb0[t];
        for (int k = 0; k < 64; ++k) accn += us[k] * nW0[(128 + k) * 128 + t];
        c0n[t] = accn;
    }
}

// ---------------- CSR build ------------------------------------------------
__global__ __launch_bounds__(256) void scan1_kernel(
    const int* __restrict__ cnt, int* __restrict__ woff, int* __restrict__ bsum, int N)
{
    __shared__ int wsum[4];
    const int t = threadIdx.x, lane = t & 63, wv = t >> 6;
    const int i0 = blockIdx.x * 1024 + t * 4;
    int v0 = (i0 + 0 < N) ? cnt[i0 + 0] : 0;
    int v1 = (i0 + 1 < N) ? cnt[i0 + 1] : 0;
    int v2 = (i0 + 2 < N) ? cnt[i0 + 2] : 0;
    int v3 = (i0 + 3 < N) ? cnt[i0 + 3] : 0;
    int ts = v0 + v1 + v2 + v3;
    int sc = ts;
    for (int d = 1; d < 64; d <<= 1) {
        int up = __shfl_up(sc, d);
        if (lane >= d) sc += up;
    }
    if (lane == 63) wsum[wv] = sc;
    __syncthreads();
    int woffs = 0;
    for (int i = 0; i < wv; ++i) woffs += wsum[i];
    int ex = woffs + sc - ts;
    if (i0 + 0 < N) woff[i0 + 0] = ex;            ex += v0;
    if (i0 + 1 < N) woff[i0 + 1] = ex;            ex += v1;
    if (i0 + 2 < N) woff[i0 + 2] = ex;            ex += v2;
    if (i0 + 3 < N) woff[i0 + 3] = ex;
    if (t == 0) bsum[blockIdx.x] = wsum[0] + wsum[1] + wsum[2] + wsum[3];
}

__global__ void scan2_kernel(int* __restrict__ bsum, int nb)
{
    __shared__ int s[256];
    const int t = threadIdx.x;
    if (t < nb) s[t] = bsum[t];
    __syncthreads();
    if (t == 0) {
        int a = 0;
        for (int i = 0; i < nb; ++i) { int v = s[i]; s[i] = a; a += v; }
    }
    __syncthreads();
    if (t < nb) bsum[t] = s[t];
}

__global__ __launch_bounds__(256) void scan3_kernel(
    int* __restrict__ woff, int* __restrict__ wcur, const int* __restrict__ bsum, int N)
{
    const int base = blockIdx.x * 1024;
    const int add = bsum[blockIdx.x];
#pragma unroll
    for (int r = 0; r < 4; ++r) {
        int i = base + r * 256 + threadIdx.x;
        if (i < N) {
            int o = woff[i] + add;
            woff[i] = o;
            wcur[i] = o;
        }
    }
}

__global__ __launch_bounds__(256) void scatter_kernel(
    const int* __restrict__ dst, int* __restrict__ wcur,
    int* __restrict__ eidx, int* __restrict__ slot, int E)
{
    int i = blockIdx.x * 256 + threadIdx.x;
    if (i < E) {
        int d = dst[i];
        int p = atomicAdd(&wcur[d], 1);
        eidx[p] = i;
        slot[i] = p;
    }
}

// ---------------- edge kernel: 64 edges / block, 4 waves, MFMA -------------
// LDS layout (40960 B -> 4 blocks/CU):
//   X  [64][192] bf16 s384 @0      (24576)  phases 0-2; H1 s256 in phases 3-4
//   H  [64][128] bf16 s256 @24576  (16384)  phases 2-3; e_new f32 s256 phase 4+
//   EF [64][64]  bf16 s128 @24576  ( 8192)  ALIAS of H, live phases 0-1 only
#define ELDS_X  0
#define ELDS_H  24576
#define ELDS_EF 24576

__global__ __launch_bounds__(256, 4) void edge_kernel(
    const float* __restrict__ ef, const unsigned short* __restrict__ vb,
    const int* __restrict__ src, const int* __restrict__ dst,
    const int* __restrict__ slot,
    const unsigned short* __restrict__ WpeT, const float* __restrict__ bpe,
    const unsigned short* __restrict__ W0T, const float* __restrict__ c0e,
    const unsigned short* __restrict__ W1T, const float* __restrict__ b1,
    const unsigned short* __restrict__ W2T, const float* __restrict__ b2,
    float* __restrict__ e_out, unsigned short* __restrict__ ebf)
{
    __shared__ __align__(16) char lds[40960];
    const int t = threadIdx.x;
    const int w = t >> 6, l = t & 63;
    const int l15 = l & 15, l4 = l >> 4;
    const int e0 = blockIdx.x * 64;

    // phase 0a: gather v[src], v[dst] FIRST (longest-latency random loads)
#pragma unroll
    for (int rr = 0; rr < 4; ++rr) {
        int f = t + 256 * rr;
        int e = f >> 4, c = f & 15;
        int node = (c < 8) ? src[e0 + e] : dst[e0 + e];
        u32x4 d = *(const u32x4*)(vb + (size_t)node * 64 + (c & 7) * 8);
        *(u32x4*)(lds + ELDS_X + swz(e, c, 384)) = d;
    }
    // phase 0b: ef fp32 -> bf16 LDS; keep f32 + slot in registers
    f32x4 efr[4];
    int sl[4];
#pragma unroll
    for (int rr = 0; rr < 4; ++rr) {
        int f = t + 256 * rr;
        int e = f >> 4, c = f & 15;
        sl[rr] = slot[e0 + e];
        efr[rr] = *(const f32x4*)(ef + (size_t)(e0 + e) * 64 + c * 4);
        u32x2 p;
        p.x = cvtpk(efr[rr][0], efr[rr][1]);
        p.y = cvtpk(efr[rr][2], efr[rr][3]);
        *(u32x2*)(lds + ELDS_EF + swz(e, c >> 1, 128) + (c & 1) * 8) = p;
    }
    // weight A-fragments (compiler chooses register residency vs reload)
    const int nrS = w * 16;
    const int nr0 = w * 32, nr1 = nr0 + 16;
    short8 Wp[2], W0f[2][6], W1f[2][4], W2f[4];
    Wp[0] = *(const short8*)(WpeT + (nrS + l15) * 64 + l4 * 8);
    Wp[1] = *(const short8*)(WpeT + (nrS + l15) * 64 + 32 + l4 * 8);
#pragma unroll
    for (int a = 0; a < 2; ++a)
#pragma unroll
        for (int ks = 0; ks < 6; ++ks)
            W0f[a][ks] = *(const short8*)(W0T + (nr0 + a * 16 + l15) * 192 + ks * 32 + l4 * 8);
#pragma unroll
    for (int a = 0; a < 2; ++a)
#pragma unroll
        for (int ks = 0; ks < 4; ++ks)
            W1f[a][ks] = *(const short8*)(W1T + (nr0 + a * 16 + l15) * 128 + ks * 32 + l4 * 8);
#pragma unroll
    for (int ks = 0; ks < 4; ++ks)
        W2f[ks] = *(const short8*)(W2T + (nrS + l15) * 128 + ks * 32 + l4 * 8);
    __syncthreads();

    // phase 1: pre-dense edge MLP (K=64, N=64) -> X cols 128..191
    {
        f32x4 bb = *(const f32x4*)(bpe + nrS + l4 * 4);
        const int ochunk = ((128 + nrS) >> 3) + (l4 >> 1), obyte = (l4 & 1) * 8;
#pragma unroll
        for (int tt = 0; tt < 4; ++tt) {
            short8 b0 = *(const short8*)(lds + ELDS_EF + swz(tt * 16 + l15, l4, 128));
            short8 b1 = *(const short8*)(lds + ELDS_EF + swz(tt * 16 + l15, 4 + l4, 128));
            f32x4 acc = {0.f, 0.f, 0.f, 0.f};
            acc = mfma16(Wp[0], b0, acc);
            acc = mfma16(Wp[1], b1, acc);
            u32x2 p;
            p.x = cvtpk(sp(acc[0] + bb[0]), sp(acc[1] + bb[1]));
            p.y = cvtpk(sp(acc[2] + bb[2]), sp(acc[3] + bb[3]));
            *(u32x2*)(lds + ELDS_X + swz(tt * 16 + l15, ochunk, 384) + obyte) = p;
        }
    }
    __syncthreads();   // all EF reads done; H region may now be overwritten

    // phase 2: layer0 (K=192, N=128) -> H0; 4 tt x 2 acc independent chains
    {
        f32x4 bb0 = *(const f32x4*)(c0e + nr0 + l4 * 4);
        f32x4 bb1 = *(const f32x4*)(c0e + nr1 + l4 * 4);
        const int oc0 = (nr0 >> 3) + (l4 >> 1), oc1 = (nr1 >> 3) + (l4 >> 1);
        const int obyte = (l4 & 1) * 8;
#pragma unroll
        for (int tt = 0; tt < 4; ++tt) {
            f32x4 a0 = {0.f, 0.f, 0.f, 0.f}, a1 = {0.f, 0.f, 0.f, 0.f};
#pragma unroll
            for (int ks = 0; ks < 6; ++ks) {
                short8 b = *(const short8*)(lds + ELDS_X + swz(tt * 16 + l15, ks * 4 + l4, 384));
                a0 = mfma16(W0f[0][ks], b, a0);
                a1 = mfma16(W0f[1][ks], b, a1);
            }
            u32x2 p0, p1;
            p0.x = cvtpk(sp(a0[0] + bb0[0]), sp(a0[1] + bb0[1]));
            p0.y = cvtpk(sp(a0[2] + bb0[2]), sp(a0[3] + bb0[3]));
            p1.x = cvtpk(sp(a1[0] + bb1[0]), sp(a1[1] + bb1[1]));
            p1.y = cvtpk(sp(a1[2] + bb1[2]), sp(a1[3] + bb1[3]));
            *(u32x2*)(lds + ELDS_H + swz(tt * 16 + l15, oc0, 256) + obyte) = p0;
            *(u32x2*)(lds + ELDS_H + swz(tt * 16 + l15, oc1, 256) + obyte) = p1;
        }
    }
    __syncthreads();

    // phase 3: layer1 (K=128, N=128): H0 -> H1 (X region, s256)
    {
        f32x4 bb0 = *(const f32x4*)(b1 + nr0 + l4 * 4);
        f32x4 bb1 = *(const f32x4*)(b1 + nr1 + l4 * 4);
        const int oc0 = (nr0 >> 3) + (l4 >> 1), oc1 = (nr1 >> 3) + (l4 >> 1);
        const int obyte = (l4 & 1) * 8;
#pragma unroll
        for (int tt = 0; tt < 4; ++tt) {
            f32x4 a0 = {0.f, 0.f, 0.f, 0.f}, a1 = {0.f, 0.f, 0.f, 0.f};
#pragma unroll
            for (int ks = 0; ks < 4; ++ks) {
                short8 b = *(const short8*)(lds + ELDS_H + swz(tt * 16 + l15, ks * 4 + l4, 256));
                a0 = mfma16(W1f[0][ks], b, a0);
                a1 = mfma16(W1f[1][ks], b, a1);
            }
            u32x2 p0, p1;
            p0.x = cvtpk(sp(a0[0] + bb0[0]), sp(a0[1] + bb0[1]));
            p0.y = cvtpk(sp(a0[2] + bb0[2]), sp(a0[3] + bb0[3]));
            p1.x = cvtpk(sp(a1[0] + bb1[0]), sp(a1[1] + bb1[1]));
            p1.y = cvtpk(sp(a1[2] + bb1[2]), sp(a1[3] + bb1[3]));
            *(u32x2*)(lds + ELDS_X + swz(tt * 16 + l15, oc0, 256) + obyte) = p0;
            *(u32x2*)(lds + ELDS_X + swz(tt * 16 + l15, oc1, 256) + obyte) = p1;
        }
    }
    __syncthreads();

    // phase 4: layer2 (K=128, N=64): H1 -> e_new (f32, H region)
    {
        f32x4 bb = *(const f32x4*)(b2 + nrS + l4 * 4);
        const int ochunk = (nrS >> 2) + l4;
#pragma unroll
        for (int tt = 0; tt < 4; ++tt) {
            f32x4 acc = {0.f, 0.f, 0.f, 0.f};
#pragma unroll
            for (int ks = 0; ks < 4; ++ks) {
                short8 b = *(const short8*)(lds + ELDS_X + swz(tt * 16 + l15, ks * 4 + l4, 256));
                acc = mfma16(W2f[ks], b, acc);
            }
            f32x4 y = {sp(acc[0] + bb[0]), sp(acc[1] + bb[1]),
                       sp(acc[2] + bb[2]), sp(acc[3] + bb[3])};
            *(f32x4*)(lds + ELDS_H + swz(tt * 16 + l15, ochunk, 256)) = y;
        }
    }
    __syncthreads();

    // phase 5: epilogue — register skip-add, coalesced f32 store, CSR-slot ebf
#pragma unroll
    for (int rr = 0; rr < 4; ++rr) {
        int f = t + 256 * rr;
        int e = f >> 4, c = f & 15;
        f32x4 en = *(const f32x4*)(lds + ELDS_H + swz(e, c, 256));
        *(f32x4*)(e_out + (size_t)(e0 + e) * 64 + c * 4) = en + efr[rr];
        if (ebf) {
            u32x2 pk;
            pk.x = cvtpk(en[0], en[1]);
            pk.y = cvtpk(en[2], en[3]);
            *(u32x2*)(ebf + (size_t)sl[rr] * 64 + c * 4) = pk;
        }
    }
}

// ---------------- node kernel: 64 nodes / block, CSR gather + MFMA ---------
#define NLDS_X 0
#define NLDS_H 16384

__global__ __launch_bounds__(256, 3) void node_kernel(
    const float* __restrict__ nf, const unsigned short* __restrict__ vb,
    const int* __restrict__ cnt, const int* __restrict__ woff,
    const int* __restrict__ eidx,
    const unsigned short* __restrict__ ebf,          // CSR-ordered bf16 e_new (or null)
    const float* __restrict__ e_out_full, const float* __restrict__ ef_full,
    const unsigned short* __restrict__ W0T, const float* __restrict__ c0n,
    const unsigned short* __restrict__ W1T, const float* __restrict__ b1,
    const unsigned short* __restrict__ W2T, const float* __restrict__ b2,
    float* __restrict__ v_out, float* __restrict__ acc_e, float* __restrict__ acc_v,
    int N)
{
    __shared__ __align__(16) char lds[32768];
    const int t = threadIdx.x;
    const int w = t >> 6, l = t & 63;
    const int l15 = l & 15, l4 = l >> 4;
    const int n0 = blockIdx.x * 64;

#pragma unroll
    for (int rr = 0; rr < 2; ++rr) {
        int f = t + 256 * rr;
        int e = f >> 3, c = f & 7;
        int n = n0 + e; if (n >= N) n = N - 1;
        u32x4 d = *(const u32x4*)(vb + (size_t)n * 64 + c * 8);
        *(u32x4*)(lds + NLDS_X + swz(e, c, 256)) = d;
    }
    {
        const int e = t >> 2, p = t & 3;
        const int n = n0 + e;
        const bool valid = n < N;
        f32x4 a0 = {0,0,0,0}, a1 = {0,0,0,0}, a2 = {0,0,0,0}, a3 = {0,0,0,0};
        float rc = 0.f;
        if (valid) {
            const int off = woff[n], deg = cnt[n];
            rc = 1.f / fmaxf((float)deg, 1.f);
            if (ebf) {
                const unsigned short* base = ebf + (size_t)off * 64 + p * 16;
                for (int j = 0; j < deg; ++j) {
                    u32x4 qa = *(const u32x4*)(base);
                    u32x4 qb = *(const u32x4*)(base + 8);
                    base += 64;
                    a0[0] += bflo(qa.x); a0[1] += bfhi(qa.x);
                    a0[2] += bflo(qa.y); a0[3] += bfhi(qa.y);
                    a1[0] += bflo(qa.z); a1[1] += bfhi(qa.z);
                    a1[2] += bflo(qa.w); a1[3] += bfhi(qa.w);
                    a2[0] += bflo(qb.x); a2[1] += bfhi(qb.x);
                    a2[2] += bflo(qb.y); a2[3] += bfhi(qb.y);
                    a3[0] += bflo(qb.z); a3[1] += bfhi(qb.z);
                    a3[2] += bflo(qb.w); a3[3] += bfhi(qb.w);
                }
            } else {
                for (int j = 0; j < deg; ++j) {
                    int ed = eidx[off + j];
                    const float* ro = e_out_full + (size_t)ed * 64 + p * 16;
                    const float* ri = ef_full + (size_t)ed * 64 + p * 16;
                    a0 += *(const f32x4*)(ro + 0)  - *(const f32x4*)(ri + 0);
                    a1 += *(const f32x4*)(ro + 4)  - *(const f32x4*)(ri + 4);
                    a2 += *(const f32x4*)(ro + 8)  - *(const f32x4*)(ri + 8);
                    a3 += *(const f32x4*)(ro + 12) - *(const f32x4*)(ri + 12);
                }
            }
        }
        *(f32x4*)(lds + NLDS_H + swz(e, p * 4 + 0, 256)) = a0;
        *(f32x4*)(lds + NLDS_H + swz(e, p * 4 + 1, 256)) = a1;
        *(f32x4*)(lds + NLDS_H + swz(e, p * 4 + 2, 256)) = a2;
        *(f32x4*)(lds + NLDS_H + swz(e, p * 4 + 3, 256)) = a3;
        *(u32x4*)(lds + NLDS_X + swz(e, 8 + 2 * p, 256)) = pack8(a0 * rc, a1 * rc);
        *(u32x4*)(lds + NLDS_X + swz(e, 9 + 2 * p, 256)) = pack8(a2 * rc, a3 * rc);
    }
    __syncthreads();
    if (t < 64) {
        float s = 0.f;
        for (int row = 0; row < 64; ++row)
            s += *(const float*)(lds + NLDS_H + swz(row, t >> 2, 256) + (t & 3) * 4);
        atomicAdd(acc_e + t, s);
    }
    __syncthreads();

    // layer0 (K=128, N=128): Xn -> H
    {
        const int nr0 = w * 32, nr1 = nr0 + 16;
        short8 A[2][4];
#pragma unroll
        for (int a = 0; a < 2; ++a)
#pragma unroll
            for (int ks = 0; ks < 4; ++ks)
                A[a][ks] = *(const short8*)(W0T + (nr0 + a * 16 + l15) * 128 + ks * 32 + l4 * 8);
        f32x4 bb0 = *(const f32x4*)(c0n + nr0 + l4 * 4);
        f32x4 bb1 = *(const f32x4*)(c0n + nr1 + l4 * 4);
        const int oc0 = (nr0 >> 3) + (l4 >> 1), oc1 = (nr1 >> 3) + (l4 >> 1);
        const int obyte = (l4 & 1) * 8;
#pragma unroll
        for (int tt = 0; tt < 4; ++tt) {
            f32x4 a0 = {0.f, 0.f, 0.f, 0.f}, a1 = {0.f, 0.f, 0.f, 0.f};
#pragma unroll
            for (int ks = 0; ks < 4; ++ks) {
                short8 b = *(const short8*)(lds + NLDS_X + swz(tt * 16 + l15, ks * 4 + l4, 256));
                a0 = mfma16(A[0][ks], b, a0);
                a1 = mfma16(A[1][ks], b, a1);
            }
            u32x2 p0, p1;
            p0.x = cvtpk(sp(a0[0] + bb0[0]), sp(a0[1] + bb0[1]));
            p0.y = cvtpk(sp(a0[2] + bb0[2]), sp(a0[3] + bb0[3]));
            p1.x = cvtpk(sp(a1[0] + bb1[0]), sp(a1[1] + bb1[1]));
            p1.y = cvtpk(sp(a1[2] + bb1[2]), sp(a1[3] + bb1[3]));
            *(u32x2*)(lds + NLDS_H + swz(tt * 16 + l15, oc0, 256) + obyte) = p0;
            *(u32x2*)(lds + NLDS_H + swz(tt * 16 + l15, oc1, 256) + obyte) = p1;
        }
    }
    __syncthreads();

    // layer1 (K=128, N=128): H -> H1 (Xn region)
    {
        const int nr0 = w * 32, nr1 = nr0 + 16;
        short8 A[2][4];
#pragma unroll
        for (int a = 0; a < 2; ++a)
#pragma unroll
            for (int ks = 0; ks < 4; ++ks)
                A[a][ks] = *(const short8*)(W1T + (nr0 + a * 16 + l15) * 128 + ks * 32 + l4 * 8);
        f32x4 bb0 = *(const f32x4*)(b1 + nr0 + l4 * 4);
        f32x4 bb1 = *(const f32x4*)(b1 + nr1 + l4 * 4);
        const int oc0 = (nr0 >> 3) + (l4 >> 1), oc1 = (nr1 >> 3) + (l4 >> 1);
        const int obyte = (l4 & 1) * 8;
#pragma unroll
        for (int tt = 0; tt < 4; ++tt) {
            f32x4 a0 = {0.f, 0.f, 0.f, 0.f}, a1 = {0.f, 0.f, 0.f, 0.f};
#pragma unroll
            for (int ks = 0; ks < 4; ++ks) {
                short8 b = *(const short8*)(lds + NLDS_H + swz(tt * 16 + l15, ks * 4 + l4, 256));
                a0 = mfma16(A[0][ks], b, a0);
                a1 = mfma16(A[1][ks], b, a1);
            }
            u32x2 p0, p1;
            p0.x = cvtpk(sp(a0[0] + bb0[0]), sp(a0[1] + bb0[1]));
            p0.y = cvtpk(sp(a0[2] + bb0[2]), sp(a0[3] + bb0[3]));
            p1.x = cvtpk(sp(a1[0] + bb1[0]), sp(a1[1] + bb1[1]));
            p1.y = cvtpk(sp(a1[2] + bb1[2]), sp(a1[3] + bb1[3]));
            *(u32x2*)(lds + NLDS_X + swz(tt * 16 + l15, oc0, 256) + obyte) = p0;
            *(u32x2*)(lds + NLDS_X + swz(tt * 16 + l15, oc1, 256) + obyte) = p1;
        }
    }
    __syncthreads();

    // layer2 (K=128, N=64): H1 -> v_new (f32, H region; zero invalid cols)
    {
        const int nr = w * 16;
        short8 A[4];
#pragma unroll
        for (int ks = 0; ks < 4; ++ks)
            A[ks] = *(const short8*)(W2T + (nr + l15) * 128 + ks * 32 + l4 * 8);
        f32x4 bb = *(const f32x4*)(b2 + nr + l4 * 4);
        const int ochunk = (nr >> 2) + l4;
#pragma unroll
        for (int tt = 0; tt < 4; ++tt) {
            f32x4 acc = {0.f, 0.f, 0.f, 0.f};
#pragma unroll
            for (int ks = 0; ks < 4; ++ks) {
                short8 b = *(const short8*)(lds + NLDS_X + swz(tt * 16 + l15, ks * 4 + l4, 256));
                acc = mfma16(A[ks], b, acc);
            }
            bool valid = (n0 + tt * 16 + l15) < N;
            f32x4 y;
            y[0] = valid ? sp(acc[0] + bb[0]) : 0.f;
            y[1] = valid ? sp(acc[1] + bb[1]) : 0.f;
            y[2] = valid ? sp(acc[2] + bb[2]) : 0.f;
            y[3] = valid ? sp(acc[3] + bb[3]) : 0.f;
            *(f32x4*)(lds + NLDS_H + swz(tt * 16 + l15, ochunk, 256)) = y;
        }
    }
    __syncthreads();

#pragma unroll
    for (int rr = 0; rr < 4; ++rr) {
        int f = t + 256 * rr;
        int e = f >> 4, c = f & 15;
        int n = n0 + e;
        if (n < N) {
            f32x4 vn = *(const f32x4*)(lds + NLDS_H + swz(e, c, 256));
            f32x4 x = *(const f32x4*)(nf + (size_t)n * 64 + c * 4);
            f32x4 o = vn + x;
            *(f32x4*)(v_out + (size_t)n * 64 + c * 4) = o;
        }
    }
    if (t < 64) {
        float s = 0.f;
        for (int row = 0; row < 64; ++row)
            s += *(const float*)(lds + NLDS_H + swz(row, t >> 2, 256) + (t & 3) * 4);
        atomicAdd(acc_v + t, s);
    }
}

// ---------------- attr kernel: single block --------------------------------
__global__ void attr_kernel(
    const float* __restrict__ ga, const float* __restrict__ u,
    const float* __restrict__ acc_e, const float* __restrict__ acc_v,
    const float* __restrict__ W0, const float* __restrict__ b0,
    const float* __restrict__ W1, const float* __restrict__ b1,
    const float* __restrict__ W2, const float* __restrict__ b2,
    float* __restrict__ out_u, float Einv, float Ninv)
{
    __shared__ float ain[192];
    __shared__ float h0[128];
    __shared__ float h1[128];
    const int t = threadIdx.x;
    if (t < 64) {
        ain[t] = u[t];
        ain[64 + t] = acc_e[t] * Einv;
        ain[128 + t] = acc_v[t] * Ninv;
    }
    __syncthreads();
    if (t < 128) {
        float a = b0[t];
        for (int k = 0; k < 192; ++k) a += ain[k] * W0[k * 128 + t];
        h0[t] = sp(a);
    }
    __syncthreads();
    if (t < 128) {
        float a = b1[t];
        for (int k = 0; k < 128; ++k) a += h0[k] * W1[k * 128 + t];
        h1[t] = sp(a);
    }
    __syncthreads();
    if (t < 64) {
        float a = b2[t];
        for (int k = 0; k < 128; ++k) a += h1[k] * W2[k * 64 + t];
        out_u[t] = sp(a) + ga[t];
    }
}

// ---------------------------------------------------------------------------
extern "C" void kernel_launch(void* const* d_in, const int* in_sizes, int n_in,
                              void* d_out, int out_size, void* d_ws, size_t ws_size,
                              hipStream_t stream)
{
    const float* edge_feat = (const float*)d_in[0];
    const float* node_feat = (const float*)d_in[1];
    const float* graph_attr = (const float*)d_in[2];
    const int*   src = (const int*)d_in[3];
    const int*   dst = (const int*)d_in[4];
    const float* pre_edge_w = (const float*)d_in[5];
    const float* pre_edge_b = (const float*)d_in[6];
    const float* pre_node_w = (const float*)d_in[7];
    const float* pre_node_b = (const float*)d_in[8];
    const float* pre_attr_w = (const float*)d_in[9];
    const float* pre_attr_b = (const float*)d_in[10];
    const float* edge_w0 = (const float*)d_in[11];
    const float* edge_b0 = (const float*)d_in[12];
    const float* edge_w1 = (const float*)d_in[13];
    const float* edge_b1 = (const float*)d_in[14];
    const float* edge_w2 = (const float*)d_in[15];
    const float* edge_b2 = (const float*)d_in[16];
    const float* node_w0 = (const float*)d_in[17];
    const float* node_b0 = (const float*)d_in[18];
    const float* node_w1 = (const float*)d_in[19];
    const float* node_b1 = (const float*)d_in[20];
    const float* node_w2 = (const float*)d_in[21];
    const float* node_b2 = (const float*)d_in[22];
    const float* attr_w0 = (const float*)d_in[23];
    const float* attr_b0 = (const float*)d_in[24];
    const float* attr_w1 = (const float*)d_in[25];
    const float* attr_b1 = (const float*)d_in[26];
    const float* attr_w2 = (const float*)d_in[27];
    const float* attr_b2 = (const float*)d_in[28];

    const int E = in_sizes[0] / 64;
    const int N = in_sizes[1] / 64;
    const int NB = (N + 1023) / 1024;           // scan blocks

    // workspace layout. acc_e | acc_v | cnt FIRST (one memset resets all).
    char* wsB = (char*)d_ws;
    size_t off = 0;
    auto alloc = [&](size_t bytes) { char* p = wsB + off; off += (bytes + 15) & ~(size_t)15; return p; };
    float* acc_e = (float*)alloc(64 * 4);
    float* acc_v = (float*)alloc(64 * 4);
    int*   cnt   = (int*)alloc((size_t)N * 4);
    float* u     = (float*)alloc(64 * 4);
    float* c0e   = (float*)alloc(128 * 4);
    float* c0n   = (float*)alloc(128 * 4);
    int*   bsum  = (int*)alloc((size_t)NB * 4);
    int*   woff  = (int*)alloc((size_t)N * 4);
    int*   wcur  = (int*)alloc((size_t)N * 4);
    int*   eidx  = (int*)alloc((size_t)E * 4);
    int*   slot  = (int*)alloc((size_t)E * 4);
    unsigned short* wT = (unsigned short*)alloc((size_t)98304 * 2);
    unsigned short* vb = (unsigned short*)alloc((size_t)N * 64 * 2);
    size_t off_no_ebf = off;
    unsigned short* ebf = (unsigned short*)alloc((size_t)E * 64 * 2);
    const bool use_ebf = (off <= ws_size);
    if (!use_ebf) { ebf = nullptr; off = off_no_ebf; }

    unsigned short* WpeT = wT;
    unsigned short* We0T = wT + 4096;
    unsigned short* We1T = wT + 28672;
    unsigned short* We2T = wT + 45056;
    unsigned short* Wn0T = wT + 53248;
    unsigned short* Wn1T = wT + 69632;
    unsigned short* Wn2T = wT + 86016;
    unsigned short* WpnT = wT + 94208;

    float* e_out = (float*)d_out;                 // E*64
    float* v_out = e_out + (size_t)E * 64;        // N*64
    float* u_out = v_out + (size_t)N * 64;        // 64

    hipMemsetAsync(acc_e, 0, (size_t)(128 + N) * 4, stream);

    wprep<<<384, 256, 0, stream>>>(pre_edge_w, edge_w0, edge_w1, edge_w2,
                                   node_w0, node_w1, node_w2, pre_node_w, wT,
                                   dst, cnt, E);
    pre_node_kernel<<<(N + 63) / 64, 256, 0, stream>>>(node_feat, WpnT, pre_node_b, vb, N);
    pre_attr_kernel<<<1, 128, 0, stream>>>(graph_attr, pre_attr_w, pre_attr_b,
                                           edge_w0, edge_b0, node_w0, node_b0,
                                           u, c0e, c0n);
    scan1_kernel<<<NB, 256, 0, stream>>>(cnt, woff, bsum, N);
    scan2_kernel<<<1, 256, 0, stream>>>(bsum, NB);
    scan3_kernel<<<NB, 256, 0, stream>>>(woff, wcur, bsum, N);
    scatter_kernel<<<(E + 255) / 256, 256, 0, stream>>>(dst, wcur, eidx, slot, E);
    edge_kernel<<<E / 64, 256, 0, stream>>>(
        edge_feat, vb, src, dst, slot,
        WpeT, pre_edge_b, We0T, c0e, We1T, edge_b1, We2T, edge_b2,
        e_out, ebf);
    node_kernel<<<(N + 63) / 64, 256, 0, stream>>>(
        node_feat, vb, cnt, woff, eidx, ebf, e_out, edge_feat,
        Wn0T, c0n, Wn1T, node_b1, Wn2T, node_b2,
        v_out, acc_e, acc_v, N);
    attr_kernel<<<1, 128, 0, stream>>>(
        graph_attr, u, acc_e, acc_v,
        attr_w0, attr_b0, attr_w1, attr_b1, attr_w2, attr_b2,
        u_out, 1.f / (float)E, 1.f / (float)N);
}

// Round 14
// 520.594 us; speedup vs baseline: 1.3832x; 1.3832x over previous
//
#include <hip/hip_runtime.h>
#include <cstddef>

// ---------------------------------------------------------------------------
// MegNet block, round 14: exact R12 edge structure restored (64-edge tile,
// 48KB LDS with OWN EF region, launch_bounds(256,3) — every (256,4+) attempt
// spilled: R5/R6/R13 all showed the WRITE_SIZE blowup). Additions vs R12:
// vb-gathers issued before ef loads; non-temporal e_out/v_out stores.
// E=800000, N=100000, D=64, H=128.
// ---------------------------------------------------------------------------

typedef __attribute__((ext_vector_type(8))) short short8;   // 8 bf16
typedef __attribute__((ext_vector_type(4))) float f32x4;
typedef __attribute__((ext_vector_type(4))) unsigned int u32x4;
typedef __attribute__((ext_vector_type(2))) unsigned int u32x2;

__device__ __forceinline__ float sp(float x) {
    return fmaxf(x, 0.f) + __logf(1.f + __expf(-fabsf(x)));
}
__device__ __forceinline__ unsigned short f2bf(float x) {
    unsigned int u = __float_as_uint(x);
    u += 0x7fff + ((u >> 16) & 1);          // RNE
    return (unsigned short)(u >> 16);
}
__device__ __forceinline__ unsigned int cvtpk(float lo, float hi) {
    unsigned int r;
    asm("v_cvt_pk_bf16_f32 %0, %1, %2" : "=v"(r) : "v"(lo), "v"(hi));
    return r;
}
__device__ __forceinline__ u32x4 pack8(f32x4 a, f32x4 b) {
    u32x4 r;
    r.x = cvtpk(a[0], a[1]); r.y = cvtpk(a[2], a[3]);
    r.z = cvtpk(b[0], b[1]); r.w = cvtpk(b[2], b[3]);
    return r;
}
__device__ __forceinline__ float bflo(unsigned int u) { return __uint_as_float(u << 16); }
__device__ __forceinline__ float bfhi(unsigned int u) { return __uint_as_float(u & 0xffff0000u); }
// 16B-chunk XOR swizzle
__device__ __forceinline__ int swz(int row, int chunk, int stride) {
    return row * stride + 128 * (chunk >> 3) + 16 * ((chunk & 7) ^ (row & 7));
}
__device__ __forceinline__ f32x4 mfma16(short8 a, short8 b, f32x4 c) {
    return __builtin_amdgcn_mfma_f32_16x16x32_bf16(a, b, c, 0, 0, 0);
}

// ---------------- weight transpose+bf16 prep (+ fused dst histogram) -------
__global__ __launch_bounds__(256) void wprep(
    const float* __restrict__ Wpe, const float* __restrict__ We0,
    const float* __restrict__ We1, const float* __restrict__ We2,
    const float* __restrict__ Wn0, const float* __restrict__ Wn1,
    const float* __restrict__ Wn2, const float* __restrict__ Wpn,
    unsigned short* __restrict__ out,
    const int* __restrict__ dst, int* __restrict__ cnt, int E)
{
    int idx = blockIdx.x * 256 + threadIdx.x;
    for (int i = idx; i < E; i += 384 * 256) atomicAdd(&cnt[dst[i]], 1);

    const float* src; int K, N, base;
    if      (idx < 4096)  { src = Wpe; K = 64;  N = 64;  base = 0; }
    else if (idx < 28672) { src = We0; K = 192; N = 128; base = 4096; }
    else if (idx < 45056) { src = We1; K = 128; N = 128; base = 28672; }
    else if (idx < 53248) { src = We2; K = 128; N = 64;  base = 45056; }
    else if (idx < 69632) { src = Wn0; K = 128; N = 128; base = 53248; }
    else if (idx < 86016) { src = Wn1; K = 128; N = 128; base = 69632; }
    else if (idx < 94208) { src = Wn2; K = 128; N = 64;  base = 86016; }
    else if (idx < 98304) { src = Wpn; K = 64;  N = 64;  base = 94208; }
    else return;
    int r = idx - base, n = r / K, k = r % K;
    out[idx] = f2bf(src[(size_t)k * N + n]);
}

// ---------------- pre-dense node MLP (MFMA) -> bf16 v ----------------------
__global__ __launch_bounds__(256) void pre_node_kernel(
    const float* __restrict__ nf, const unsigned short* __restrict__ WpnT,
    const float* __restrict__ b, unsigned short* __restrict__ vb, int N)
{
    __shared__ __align__(16) char lds[16384];
    const int t = threadIdx.x, w = t >> 6, l = t & 63;
    const int l15 = l & 15, l4 = l >> 4;
    const int n0 = blockIdx.x * 64;

#pragma unroll
    for (int rr = 0; rr < 2; ++rr) {
        int f = t + 256 * rr;
        int e = f >> 3, c = f & 7;
        int n = n0 + e; if (n >= N) n = N - 1;
        const float* p = nf + (size_t)n * 64 + c * 8;
        f32x4 x0 = *(const f32x4*)p, x1 = *(const f32x4*)(p + 4);
        *(u32x4*)(lds + swz(e, c, 128)) = pack8(x0, x1);
    }
    __syncthreads();
    {
        const int nr = w * 16;
        short8 A0 = *(const short8*)(WpnT + (nr + l15) * 64 + l4 * 8);
        short8 A1 = *(const short8*)(WpnT + (nr + l15) * 64 + 32 + l4 * 8);
        f32x4 bb = *(const f32x4*)(b + nr + l4 * 4);
        const int ochunk = (nr >> 3) + (l4 >> 1), obyte = (l4 & 1) * 8;
#pragma unroll
        for (int tt = 0; tt < 4; ++tt) {
            short8 b0 = *(const short8*)(lds + swz(tt * 16 + l15, l4, 128));
            short8 b1 = *(const short8*)(lds + swz(tt * 16 + l15, 4 + l4, 128));
            f32x4 acc = {0.f, 0.f, 0.f, 0.f};
            acc = mfma16(A0, b0, acc);
            acc = mfma16(A1, b1, acc);
            u32x2 p;
            p.x = cvtpk(sp(acc[0] + bb[0]), sp(acc[1] + bb[1]));
            p.y = cvtpk(sp(acc[2] + bb[2]), sp(acc[3] + bb[3]));
            *(u32x2*)(lds + 8192 + swz(tt * 16 + l15, ochunk, 128) + obyte) = p;
        }
    }
    __syncthreads();
#pragma unroll
    for (int rr = 0; rr < 2; ++rr) {
        int f = t + 256 * rr;
        int e = f >> 3, c = f & 7;
        int n = n0 + e;
        if (n < N) {
            u32x4 d = *(const u32x4*)(lds + 8192 + swz(e, c, 128));
            *(u32x4*)(vb + (size_t)n * 64 + c * 8) = d;
        }
    }
}

// -------- pre-dense attr + fold u into edge/node layer-0 biases ------------
__global__ void pre_attr_kernel(
    const float* __restrict__ ga, const float* __restrict__ Wpa, const float* __restrict__ bpa,
    const float* __restrict__ eW0, const float* __restrict__ eb0,
    const float* __restrict__ nW0, const float* __restrict__ nb0,
    float* __restrict__ u, float* __restrict__ c0e, float* __restrict__ c0n)
{
    __shared__ float us[64];
    const int t = threadIdx.x;
    if (t < 64) {
        float acc = bpa[t];
        for (int k = 0; k < 64; ++k) acc += ga[k] * Wpa[k * 64 + t];
        float uu = sp(acc);
        us[t] = uu;
        u[t] = uu;
    }
    __syncthreads();
    if (t < 128) {
        float acc = eb0[t];
        for (int k = 0; k < 64; ++k) acc += us[k] * eW0[(192 + k) * 128 + t];
        c0e[t] = acc;
        float accn = nb0[t];
        for (int k = 0; k < 64; ++k) accn += us[k] * nW0[(128 + k) * 128 + t];
        c0n[t] = accn;
    }
}

// ---------------- CSR build ------------------------------------------------
__global__ __launch_bounds__(256) void scan1_kernel(
    const int* __restrict__ cnt, int* __restrict__ woff, int* __restrict__ bsum, int N)
{
    __shared__ int wsum[4];
    const int t = threadIdx.x, lane = t & 63, wv = t >> 6;
    const int i0 = blockIdx.x * 1024 + t * 4;
    int v0 = (i0 + 0 < N) ? cnt[i0 + 0] : 0;
    int v1 = (i0 + 1 < N) ? cnt[i0 + 1] : 0;
    int v2 = (i0 + 2 < N) ? cnt[i0 + 2] : 0;
    int v3 = (i0 + 3 < N) ? cnt[i0 + 3] : 0;
    int ts = v0 + v1 + v2 + v3;
    int sc = ts;
    for (int d = 1; d < 64; d <<= 1) {
        int up = __shfl_up(sc, d);
        if (lane >= d) sc += up;
    }
    if (lane == 63) wsum[wv] = sc;
    __syncthreads();
    int woffs = 0;
    for (int i = 0; i < wv; ++i) woffs += wsum[i];
    int ex = woffs + sc - ts;
    if (i0 + 0 < N) woff[i0 + 0] = ex;            ex += v0;
    if (i0 + 1 < N) woff[i0 + 1] = ex;            ex += v1;
    if (i0 + 2 < N) woff[i0 + 2] = ex;            ex += v2;
    if (i0 + 3 < N) woff[i0 + 3] = ex;
    if (t == 0) bsum[blockIdx.x] = wsum[0] + wsum[1] + wsum[2] + wsum[3];
}

__global__ void scan2_kernel(int* __restrict__ bsum, int nb)
{
    __shared__ int s[256];
    const int t = threadIdx.x;
    if (t < nb) s[t] = bsum[t];
    __syncthreads();
    if (t == 0) {
        int a = 0;
        for (int i = 0; i < nb; ++i) { int v = s[i]; s[i] = a; a += v; }
    }
    __syncthreads();
    if (t < nb) bsum[t] = s[t];
}

__global__ __launch_bounds__(256) void scan3_kernel(
    int* __restrict__ woff, int* __restrict__ wcur, const int* __restrict__ bsum, int N)
{
    const int base = blockIdx.x * 1024;
    const int add = bsum[blockIdx.x];
#pragma unroll
    for (int r = 0; r < 4; ++r) {
        int i = base + r * 256 + threadIdx.x;
        if (i < N) {
            int o = woff[i] + add;
            woff[i] = o;
            wcur[i] = o;
        }
    }
}

__global__ __launch_bounds__(256) void scatter_kernel(
    const int* __restrict__ dst, int* __restrict__ wcur,
    int* __restrict__ eidx, int* __restrict__ slot, int E)
{
    int i = blockIdx.x * 256 + threadIdx.x;
    if (i < E) {
        int d = dst[i];
        int p = atomicAdd(&wcur[d], 1);
        eidx[p] = i;
        slot[i] = p;
    }
}

// ---------------- edge kernel: 64 edges / block, 4 waves, MFMA -------------
// LDS layout (49152 B -> 3 blocks/CU), EXACT R12:
//   X  [64][192] bf16 s384 @0      (24576)  phases 0-2; H1 s256 in phases 3-4
//   H  [64][128] bf16 s256 @24576  (16384)  phases 2-3; e_new f32 s256 phase 4+
//   EF [64][64]  bf16 s128 @40960  ( 8192)  phases 0-1 (own region, NO alias)
#define ELDS_X  0
#define ELDS_H  24576
#define ELDS_EF 40960

__global__ __launch_bounds__(256, 3) void edge_kernel(
    const float* __restrict__ ef, const unsigned short* __restrict__ vb,
    const int* __restrict__ src, const int* __restrict__ dst,
    const int* __restrict__ slot,
    const unsigned short* __restrict__ WpeT, const float* __restrict__ bpe,
    const unsigned short* __restrict__ W0T, const float* __restrict__ c0e,
    const unsigned short* __restrict__ W1T, const float* __restrict__ b1,
    const unsigned short* __restrict__ W2T, const float* __restrict__ b2,
    float* __restrict__ e_out, unsigned short* __restrict__ ebf)
{
    __shared__ __align__(16) char lds[49152];
    const int t = threadIdx.x;
    const int w = t >> 6, l = t & 63;
    const int l15 = l & 15, l4 = l >> 4;
    const int e0 = blockIdx.x * 64;

    // phase 0a: gather v[src], v[dst] FIRST (longest-latency random loads)
#pragma unroll
    for (int rr = 0; rr < 4; ++rr) {
        int f = t + 256 * rr;
        int e = f >> 4, c = f & 15;
        int node = (c < 8) ? src[e0 + e] : dst[e0 + e];
        u32x4 d = *(const u32x4*)(vb + (size_t)node * 64 + (c & 7) * 8);
        *(u32x4*)(lds + ELDS_X + swz(e, c, 384)) = d;
    }
    // phase 0b: ef fp32 -> bf16 LDS; keep f32 + slot in registers
    f32x4 efr[4];
    int sl[4];
#pragma unroll
    for (int rr = 0; rr < 4; ++rr) {
        int f = t + 256 * rr;
        int e = f >> 4, c = f & 15;
        sl[rr] = slot[e0 + e];
        efr[rr] = *(const f32x4*)(ef + (size_t)(e0 + e) * 64 + c * 4);
        u32x2 p;
        p.x = cvtpk(efr[rr][0], efr[rr][1]);
        p.y = cvtpk(efr[rr][2], efr[rr][3]);
        *(u32x2*)(lds + ELDS_EF + swz(e, c >> 1, 128) + (c & 1) * 8) = p;
    }
    // weight A-fragments (compiler chooses register residency vs reload)
    const int nrS = w * 16;
    const int nr0 = w * 32, nr1 = nr0 + 16;
    short8 Wp[2], W0f[2][6], W1f[2][4], W2f[4];
    Wp[0] = *(const short8*)(WpeT + (nrS + l15) * 64 + l4 * 8);
    Wp[1] = *(const short8*)(WpeT + (nrS + l15) * 64 + 32 + l4 * 8);
#pragma unroll
    for (int a = 0; a < 2; ++a)
#pragma unroll
        for (int ks = 0; ks < 6; ++ks)
            W0f[a][ks] = *(const short8*)(W0T + (nr0 + a * 16 + l15) * 192 + ks * 32 + l4 * 8);
#pragma unroll
    for (int a = 0; a < 2; ++a)
#pragma unroll
        for (int ks = 0; ks < 4; ++ks)
            W1f[a][ks] = *(const short8*)(W1T + (nr0 + a * 16 + l15) * 128 + ks * 32 + l4 * 8);
#pragma unroll
    for (int ks = 0; ks < 4; ++ks)
        W2f[ks] = *(const short8*)(W2T + (nrS + l15) * 128 + ks * 32 + l4 * 8);
    __syncthreads();

    // phase 1: pre-dense edge MLP (K=64, N=64) -> X cols 128..191
    {
        f32x4 bb = *(const f32x4*)(bpe + nrS + l4 * 4);
        const int ochunk = ((128 + nrS) >> 3) + (l4 >> 1), obyte = (l4 & 1) * 8;
#pragma unroll
        for (int tt = 0; tt < 4; ++tt) {
            short8 b0 = *(const short8*)(lds + ELDS_EF + swz(tt * 16 + l15, l4, 128));
            short8 b1 = *(const short8*)(lds + ELDS_EF + swz(tt * 16 + l15, 4 + l4, 128));
            f32x4 acc = {0.f, 0.f, 0.f, 0.f};
            acc = mfma16(Wp[0], b0, acc);
            acc = mfma16(Wp[1], b1, acc);
            u32x2 p;
            p.x = cvtpk(sp(acc[0] + bb[0]), sp(acc[1] + bb[1]));
            p.y = cvtpk(sp(acc[2] + bb[2]), sp(acc[3] + bb[3]));
            *(u32x2*)(lds + ELDS_X + swz(tt * 16 + l15, ochunk, 384) + obyte) = p;
        }
    }
    __syncthreads();

    // phase 2: layer0 (K=192, N=128) -> H0; 4 tt x 2 acc independent chains
    {
        f32x4 bb0 = *(const f32x4*)(c0e + nr0 + l4 * 4);
        f32x4 bb1 = *(const f32x4*)(c0e + nr1 + l4 * 4);
        const int oc0 = (nr0 >> 3) + (l4 >> 1), oc1 = (nr1 >> 3) + (l4 >> 1);
        const int obyte = (l4 & 1) * 8;
#pragma unroll
        for (int tt = 0; tt < 4; ++tt) {
            f32x4 a0 = {0.f, 0.f, 0.f, 0.f}, a1 = {0.f, 0.f, 0.f, 0.f};
#pragma unroll
            for (int ks = 0; ks < 6; ++ks) {
                short8 b = *(const short8*)(lds + ELDS_X + swz(tt * 16 + l15, ks * 4 + l4, 384));
                a0 = mfma16(W0f[0][ks], b, a0);
                a1 = mfma16(W0f[1][ks], b, a1);
            }
            u32x2 p0, p1;
            p0.x = cvtpk(sp(a0[0] + bb0[0]), sp(a0[1] + bb0[1]));
            p0.y = cvtpk(sp(a0[2] + bb0[2]), sp(a0[3] + bb0[3]));
            p1.x = cvtpk(sp(a1[0] + bb1[0]), sp(a1[1] + bb1[1]));
            p1.y = cvtpk(sp(a1[2] + bb1[2]), sp(a1[3] + bb1[3]));
            *(u32x2*)(lds + ELDS_H + swz(tt * 16 + l15, oc0, 256) + obyte) = p0;
            *(u32x2*)(lds + ELDS_H + swz(tt * 16 + l15, oc1, 256) + obyte) = p1;
        }
    }
    __syncthreads();

    // phase 3: layer1 (K=128, N=128): H0 -> H1 (X region, s256)
    {
        f32x4 bb0 = *(const f32x4*)(b1 + nr0 + l4 * 4);
        f32x4 bb1 = *(const f32x4*)(b1 + nr1 + l4 * 4);
        const int oc0 = (nr0 >> 3) + (l4 >> 1), oc1 = (nr1 >> 3) + (l4 >> 1);
        const int obyte = (l4 & 1) * 8;
#pragma unroll
        for (int tt = 0; tt < 4; ++tt) {
            f32x4 a0 = {0.f, 0.f, 0.f, 0.f}, a1 = {0.f, 0.f, 0.f, 0.f};
#pragma unroll
            for (int ks = 0; ks < 4; ++ks) {
                short8 b = *(const short8*)(lds + ELDS_H + swz(tt * 16 + l15, ks * 4 + l4, 256));
                a0 = mfma16(W1f[0][ks], b, a0);
                a1 = mfma16(W1f[1][ks], b, a1);
            }
            u32x2 p0, p1;
            p0.x = cvtpk(sp(a0[0] + bb0[0]), sp(a0[1] + bb0[1]));
            p0.y = cvtpk(sp(a0[2] + bb0[2]), sp(a0[3] + bb0[3]));
            p1.x = cvtpk(sp(a1[0] + bb1[0]), sp(a1[1] + bb1[1]));
            p1.y = cvtpk(sp(a1[2] + bb1[2]), sp(a1[3] + bb1[3]));
            *(u32x2*)(lds + ELDS_X + swz(tt * 16 + l15, oc0, 256) + obyte) = p0;
            *(u32x2*)(lds + ELDS_X + swz(tt * 16 + l15, oc1, 256) + obyte) = p1;
        }
    }
    __syncthreads();

    // phase 4: layer2 (K=128, N=64): H1 -> e_new (f32, H region)
    {
        f32x4 bb = *(const f32x4*)(b2 + nrS + l4 * 4);
        const int ochunk = (nrS >> 2) + l4;
#pragma unroll
        for (int tt = 0; tt < 4; ++tt) {
            f32x4 acc = {0.f, 0.f, 0.f, 0.f};
#pragma unroll
            for (int ks = 0; ks < 4; ++ks) {
                short8 b = *(const short8*)(lds + ELDS_X + swz(tt * 16 + l15, ks * 4 + l4, 256));
                acc = mfma16(W2f[ks], b, acc);
            }
            f32x4 y = {sp(acc[0] + bb[0]), sp(acc[1] + bb[1]),
                       sp(acc[2] + bb[2]), sp(acc[3] + bb[3])};
            *(f32x4*)(lds + ELDS_H + swz(tt * 16 + l15, ochunk, 256)) = y;
        }
    }
    __syncthreads();

    // phase 5: epilogue — register skip-add, NONTEMPORAL e_out, CSR-slot ebf
#pragma unroll
    for (int rr = 0; rr < 4; ++rr) {
        int f = t + 256 * rr;
        int e = f >> 4, c = f & 15;
        f32x4 en = *(const f32x4*)(lds + ELDS_H + swz(e, c, 256));
        f32x4 o = en + efr[rr];
        __builtin_nontemporal_store(o, (f32x4*)(e_out + (size_t)(e0 + e) * 64 + c * 4));
        if (ebf) {
            u32x2 pk;
            pk.x = cvtpk(en[0], en[1]);
            pk.y = cvtpk(en[2], en[3]);
            *(u32x2*)(ebf + (size_t)sl[rr] * 64 + c * 4) = pk;
        }
    }
}

// ---------------- node kernel: 64 nodes / block, CSR gather + MFMA ---------
#define NLDS_X 0
#define NLDS_H 16384

__global__ __launch_bounds__(256, 3) void node_kernel(
    const float* __restrict__ nf, const unsigned short* __restrict__ vb,
    const int* __restrict__ cnt, const int* __restrict__ woff,
    const int* __restrict__ eidx,
    const unsigned short* __restrict__ ebf,          // CSR-ordered bf16 e_new (or null)
    const float* __restrict__ e_out_full, const float* __restrict__ ef_full,
    const unsigned short* __restrict__ W0T, const float* __restrict__ c0n,
    const unsigned short* __restrict__ W1T, const float* __restrict__ b1,
    const unsigned short* __restrict__ W2T, const float* __restrict__ b2,
    float* __restrict__ v_out, float* __restrict__ acc_e, float* __restrict__ acc_v,
    int N)
{
    __shared__ __align__(16) char lds[32768];
    const int t = threadIdx.x;
    const int w = t >> 6, l = t & 63;
    const int l15 = l & 15, l4 = l >> 4;
    const int n0 = blockIdx.x * 64;

#pragma unroll
    for (int rr = 0; rr < 2; ++rr) {
        int f = t + 256 * rr;
        int e = f >> 3, c = f & 7;
        int n = n0 + e; if (n >= N) n = N - 1;
        u32x4 d = *(const u32x4*)(vb + (size_t)n * 64 + c * 8);
        *(u32x4*)(lds + NLDS_X + swz(e, c, 256)) = d;
    }
    {
        const int e = t >> 2, p = t & 3;
        const int n = n0 + e;
        const bool valid = n < N;
        f32x4 a0 = {0,0,0,0}, a1 = {0,0,0,0}, a2 = {0,0,0,0}, a3 = {0,0,0,0};
        float rc = 0.f;
        if (valid) {
            const int off = woff[n], deg = cnt[n];
            rc = 1.f / fmaxf((float)deg, 1.f);
            if (ebf) {
                const unsigned short* base = ebf + (size_t)off * 64 + p * 16;
                for (int j = 0; j < deg; ++j) {
                    u32x4 qa = *(const u32x4*)(base);
                    u32x4 qb = *(const u32x4*)(base + 8);
                    base += 64;
                    a0[0] += bflo(qa.x); a0[1] += bfhi(qa.x);
                    a0[2] += bflo(qa.y); a0[3] += bfhi(qa.y);
                    a1[0] += bflo(qa.z); a1[1] += bfhi(qa.z);
                    a1[2] += bflo(qa.w); a1[3] += bfhi(qa.w);
                    a2[0] += bflo(qb.x); a2[1] += bfhi(qb.x);
                    a2[2] += bflo(qb.y); a2[3] += bfhi(qb.y);
                    a3[0] += bflo(qb.z); a3[1] += bfhi(qb.z);
                    a3[2] += bflo(qb.w); a3[3] += bfhi(qb.w);
                }
            } else {
                for (int j = 0; j < deg; ++j) {
                    int ed = eidx[off + j];
                    const float* ro = e_out_full + (size_t)ed * 64 + p * 16;
                    const float* ri = ef_full + (size_t)ed * 64 + p * 16;
                    a0 += *(const f32x4*)(ro + 0)  - *(const f32x4*)(ri + 0);
                    a1 += *(const f32x4*)(ro + 4)  - *(const f32x4*)(ri + 4);
                    a2 += *(const f32x4*)(ro + 8)  - *(const f32x4*)(ri + 8);
                    a3 += *(const f32x4*)(ro + 12) - *(const f32x4*)(ri + 12);
                }
            }
        }
        *(f32x4*)(lds + NLDS_H + swz(e, p * 4 + 0, 256)) = a0;
        *(f32x4*)(lds + NLDS_H + swz(e, p * 4 + 1, 256)) = a1;
        *(f32x4*)(lds + NLDS_H + swz(e, p * 4 + 2, 256)) = a2;
        *(f32x4*)(lds + NLDS_H + swz(e, p * 4 + 3, 256)) = a3;
        *(u32x4*)(lds + NLDS_X + swz(e, 8 + 2 * p, 256)) = pack8(a0 * rc, a1 * rc);
        *(u32x4*)(lds + NLDS_X + swz(e, 9 + 2 * p, 256)) = pack8(a2 * rc, a3 * rc);
    }
    __syncthreads();
    if (t < 64) {
        float s = 0.f;
        for (int row = 0; row < 64; ++row)
            s += *(const float*)(lds + NLDS_H + swz(row, t >> 2, 256) + (t & 3) * 4);
        atomicAdd(acc_e + t, s);
    }
    __syncthreads();

    // layer0 (K=128, N=128): Xn -> H
    {
        const int nr0 = w * 32, nr1 = nr0 + 16;
        short8 A[2][4];
#pragma unroll
        for (int a = 0; a < 2; ++a)
#pragma unroll
            for (int ks = 0; ks < 4; ++ks)
                A[a][ks] = *(const short8*)(W0T + (nr0 + a * 16 + l15) * 128 + ks * 32 + l4 * 8);
        f32x4 bb0 = *(const f32x4*)(c0n + nr0 + l4 * 4);
        f32x4 bb1 = *(const f32x4*)(c0n + nr1 + l4 * 4);
        const int oc0 = (nr0 >> 3) + (l4 >> 1), oc1 = (nr1 >> 3) + (l4 >> 1);
        const int obyte = (l4 & 1) * 8;
#pragma unroll
        for (int tt = 0; tt < 4; ++tt) {
            f32x4 a0 = {0.f, 0.f, 0.f, 0.f}, a1 = {0.f, 0.f, 0.f, 0.f};
#pragma unroll
            for (int ks = 0; ks < 4; ++ks) {
                short8 b = *(const short8*)(lds + NLDS_X + swz(tt * 16 + l15, ks * 4 + l4, 256));
                a0 = mfma16(A[0][ks], b, a0);
                a1 = mfma16(A[1][ks], b, a1);
            }
            u32x2 p0, p1;
            p0.x = cvtpk(sp(a0[0] + bb0[0]), sp(a0[1] + bb0[1]));
            p0.y = cvtpk(sp(a0[2] + bb0[2]), sp(a0[3] + bb0[3]));
            p1.x = cvtpk(sp(a1[0] + bb1[0]), sp(a1[1] + bb1[1]));
            p1.y = cvtpk(sp(a1[2] + bb1[2]), sp(a1[3] + bb1[3]));
            *(u32x2*)(lds + NLDS_H + swz(tt * 16 + l15, oc0, 256) + obyte) = p0;
            *(u32x2*)(lds + NLDS_H + swz(tt * 16 + l15, oc1, 256) + obyte) = p1;
        }
    }
    __syncthreads();

    // layer1 (K=128, N=128): H -> H1 (Xn region)
    {
        const int nr0 = w * 32, nr1 = nr0 + 16;
        short8 A[2][4];
#pragma unroll
        for (int a = 0; a < 2; ++a)
#pragma unroll
            for (int ks = 0; ks < 4; ++ks)
                A[a][ks] = *(const short8*)(W1T + (nr0 + a * 16 + l15) * 128 + ks * 32 + l4 * 8);
        f32x4 bb0 = *(const f32x4*)(b1 + nr0 + l4 * 4);
        f32x4 bb1 = *(const f32x4*)(b1 + nr1 + l4 * 4);
        const int oc0 = (nr0 >> 3) + (l4 >> 1), oc1 = (nr1 >> 3) + (l4 >> 1);
        const int obyte = (l4 & 1) * 8;
#pragma unroll
        for (int tt = 0; tt < 4; ++tt) {
            f32x4 a0 = {0.f, 0.f, 0.f, 0.f}, a1 = {0.f, 0.f, 0.f, 0.f};
#pragma unroll
            for (int ks = 0; ks < 4; ++ks) {
                short8 b = *(const short8*)(lds + NLDS_H + swz(tt * 16 + l15, ks * 4 + l4, 256));
                a0 = mfma16(A[0][ks], b, a0);
                a1 = mfma16(A[1][ks], b, a1);
            }
            u32x2 p0, p1;
            p0.x = cvtpk(sp(a0[0] + bb0[0]), sp(a0[1] + bb0[1]));
            p0.y = cvtpk(sp(a0[2] + bb0[2]), sp(a0[3] + bb0[3]));
            p1.x = cvtpk(sp(a1[0] + bb1[0]), sp(a1[1] + bb1[1]));
            p1.y = cvtpk(sp(a1[2] + bb1[2]), sp(a1[3] + bb1[3]));
            *(u32x2*)(lds + NLDS_X + swz(tt * 16 + l15, oc0, 256) + obyte) = p0;
            *(u32x2*)(lds + NLDS_X + swz(tt * 16 + l15, oc1, 256) + obyte) = p1;
        }
    }
    __syncthreads();

    // layer2 (K=128, N=64): H1 -> v_new (f32, H region; zero invalid cols)
    {
        const int nr = w * 16;
        short8 A[4];
#pragma unroll
        for (int ks = 0; ks < 4; ++ks)
            A[ks] = *(const short8*)(W2T + (nr + l15) * 128 + ks * 32 + l4 * 8);
        f32x4 bb = *(const f32x4*)(b2 + nr + l4 * 4);
        const int ochunk = (nr >> 2) + l4;
#pragma unroll
        for (int tt = 0; tt < 4; ++tt) {
            f32x4 acc = {0.f, 0.f, 0.f, 0.f};
#pragma unroll
            for (int ks = 0; ks < 4; ++ks) {
                short8 b = *(const short8*)(lds + NLDS_X + swz(tt * 16 + l15, ks * 4 + l4, 256));
                acc = mfma16(A[ks], b, acc);
            }
            bool valid = (n0 + tt * 16 + l15) < N;
            f32x4 y;
            y[0] = valid ? sp(acc[0] + bb[0]) : 0.f;
            y[1] = valid ? sp(acc[1] + bb[1]) : 0.f;
            y[2] = valid ? sp(acc[2] + bb[2]) : 0.f;
            y[3] = valid ? sp(acc[3] + bb[3]) : 0.f;
            *(f32x4*)(lds + NLDS_H + swz(tt * 16 + l15, ochunk, 256)) = y;
        }
    }
    __syncthreads();

#pragma unroll
    for (int rr = 0; rr < 4; ++rr) {
        int f = t + 256 * rr;
        int e = f >> 4, c = f & 15;
        int n = n0 + e;
        if (n < N) {
            f32x4 vn = *(const f32x4*)(lds + NLDS_H + swz(e, c, 256));
            f32x4 x = *(const f32x4*)(nf + (size_t)n * 64 + c * 4);
            f32x4 o = vn + x;
            __builtin_nontemporal_store(o, (f32x4*)(v_out + (size_t)n * 64 + c * 4));
        }
    }
    if (t < 64) {
        float s = 0.f;
        for (int row = 0; row < 64; ++row)
            s += *(const float*)(lds + NLDS_H + swz(row, t >> 2, 256) + (t & 3) * 4);
        atomicAdd(acc_v + t, s);
    }
}

// ---------------- attr kernel: single block --------------------------------
__global__ void attr_kernel(
    const float* __restrict__ ga, const float* __restrict__ u,
    const float* __restrict__ acc_e, const float* __restrict__ acc_v,
    const float* __restrict__ W0, const float* __restrict__ b0,
    const float* __restrict__ W1, const float* __restrict__ b1,
    const float* __restrict__ W2, const float* __restrict__ b2,
    float* __restrict__ out_u, float Einv, float Ninv)
{
    __shared__ float ain[192];
    __shared__ float h0[128];
    __shared__ float h1[128];
    const int t = threadIdx.x;
    if (t < 64) {
        ain[t] = u[t];
        ain[64 + t] = acc_e[t] * Einv;
        ain[128 + t] = acc_v[t] * Ninv;
    }
    __syncthreads();
    if (t < 128) {
        float a = b0[t];
        for (int k = 0; k < 192; ++k) a += ain[k] * W0[k * 128 + t];
        h0[t] = sp(a);
    }
    __syncthreads();
    if (t < 128) {
        float a = b1[t];
        for (int k = 0; k < 128; ++k) a += h0[k] * W1[k * 128 + t];
        h1[t] = sp(a);
    }
    __syncthreads();
    if (t < 64) {
        float a = b2[t];
        for (int k = 0; k < 128; ++k) a += h1[k] * W2[k * 64 + t];
        out_u[t] = sp(a) + ga[t];
    }
}

// ---------------------------------------------------------------------------
extern "C" void kernel_launch(void* const* d_in, const int* in_sizes, int n_in,
                              void* d_out, int out_size, void* d_ws, size_t ws_size,
                              hipStream_t stream)
{
    const float* edge_feat = (const float*)d_in[0];
    const float* node_feat = (const float*)d_in[1];
    const float* graph_attr = (const float*)d_in[2];
    const int*   src = (const int*)d_in[3];
    const int*   dst = (const int*)d_in[4];
    const float* pre_edge_w = (const float*)d_in[5];
    const float* pre_edge_b = (const float*)d_in[6];
    const float* pre_node_w = (const float*)d_in[7];
    const float* pre_node_b = (const float*)d_in[8];
    const float* pre_attr_w = (const float*)d_in[9];
    const float* pre_attr_b = (const float*)d_in[10];
    const float* edge_w0 = (const float*)d_in[11];
    const float* edge_b0 = (const float*)d_in[12];
    const float* edge_w1 = (const float*)d_in[13];
    const float* edge_b1 = (const float*)d_in[14];
    const float* edge_w2 = (const float*)d_in[15];
    const float* edge_b2 = (const float*)d_in[16];
    const float* node_w0 = (const float*)d_in[17];
    const float* node_b0 = (const float*)d_in[18];
    const float* node_w1 = (const float*)d_in[19];
    const float* node_b1 = (const float*)d_in[20];
    const float* node_w2 = (const float*)d_in[21];
    const float* node_b2 = (const float*)d_in[22];
    const float* attr_w0 = (const float*)d_in[23];
    const float* attr_b0 = (const float*)d_in[24];
    const float* attr_w1 = (const float*)d_in[25];
    const float* attr_b1 = (const float*)d_in[26];
    const float* attr_w2 = (const float*)d_in[27];
    const float* attr_b2 = (const float*)d_in[28];

    const int E = in_sizes[0] / 64;
    const int N = in_sizes[1] / 64;
    const int NB = (N + 1023) / 1024;           // scan blocks

    // workspace layout. acc_e | acc_v | cnt FIRST (one memset resets all).
    char* wsB = (char*)d_ws;
    size_t off = 0;
    auto alloc = [&](size_t bytes) { char* p = wsB + off; off += (bytes + 15) & ~(size_t)15; return p; };
    float* acc_e = (float*)alloc(64 * 4);
    float* acc_v = (float*)alloc(64 * 4);
    int*   cnt   = (int*)alloc((size_t)N * 4);
    float* u     = (float*)alloc(64 * 4);
    float* c0e   = (float*)alloc(128 * 4);
    float* c0n   = (float*)alloc(128 * 4);
    int*   bsum  = (int*)alloc((size_t)NB * 4);
    int*   woff  = (int*)alloc((size_t)N * 4);
    int*   wcur  = (int*)alloc((size_t)N * 4);
    int*   eidx  = (int*)alloc((size_t)E * 4);
    int*   slot  = (int*)alloc((size_t)E * 4);
    unsigned short* wT = (unsigned short*)alloc((size_t)98304 * 2);
    unsigned short* vb = (unsigned short*)alloc((size_t)N * 64 * 2);
    size_t off_no_ebf = off;
    unsigned short* ebf = (unsigned short*)alloc((size_t)E * 64 * 2);
    const bool use_ebf = (off <= ws_size);
    if (!use_ebf) { ebf = nullptr; off = off_no_ebf; }

    unsigned short* WpeT = wT;
    unsigned short* We0T = wT + 4096;
    unsigned short* We1T = wT + 28672;
    unsigned short* We2T = wT + 45056;
    unsigned short* Wn0T = wT + 53248;
    unsigned short* Wn1T = wT + 69632;
    unsigned short* Wn2T = wT + 86016;
    unsigned short* WpnT = wT + 94208;

    float* e_out = (float*)d_out;                 // E*64
    float* v_out = e_out + (size_t)E * 64;        // N*64
    float* u_out = v_out + (size_t)N * 64;        // 64

    hipMemsetAsync(acc_e, 0, (size_t)(128 + N) * 4, stream);

    wprep<<<384, 256, 0, stream>>>(pre_edge_w, edge_w0, edge_w1, edge_w2,
                                   node_w0, node_w1, node_w2, pre_node_w, wT,
                                   dst, cnt, E);
    pre_node_kernel<<<(N + 63) / 64, 256, 0, stream>>>(node_feat, WpnT, pre_node_b, vb, N);
    pre_attr_kernel<<<1, 128, 0, stream>>>(graph_attr, pre_attr_w, pre_attr_b,
                                           edge_w0, edge_b0, node_w0, node_b0,
                                           u, c0e, c0n);
    scan1_kernel<<<NB, 256, 0, stream>>>(cnt, woff, bsum, N);
    scan2_kernel<<<1, 256, 0, stream>>>(bsum, NB);
    scan3_kernel<<<NB, 256, 0, stream>>>(woff, wcur, bsum, N);
    scatter_kernel<<<(E + 255) / 256, 256, 0, stream>>>(dst, wcur, eidx, slot, E);
    edge_kernel<<<E / 64, 256, 0, stream>>>(
        edge_feat, vb, src, dst, slot,
        WpeT, pre_edge_b, We0T, c0e, We1T, edge_b1, We2T, edge_b2,
        e_out, ebf);
    node_kernel<<<(N + 63) / 64, 256, 0, stream>>>(
        node_feat, vb, cnt, woff, eidx, ebf, e_out, edge_feat,
        Wn0T, c0n, Wn1T, node_b1, Wn2T, node_b2,
        v_out, acc_e, acc_v, N);
    attr_kernel<<<1, 128, 0, stream>>>(
        graph_attr, u, acc_e, acc_v,
        attr_w0, attr_b0, attr_w1, attr_b1, attr_w2, attr_b2,
        u_out, 1.f / (float)E, 1.f / (float)N);
}